// Round 2
// baseline (548.940 us; speedup 1.0000x reference)
//
#include <hip/hip_runtime.h>
#include <hip/hip_bf16.h>
#include <cstdint>

// LocalRNN: B=16 L=1024 D=256 H=256 K=16, GRU over K-window per position.
// All device buffers are FP32 (reference dtypes). MFMA runs on bf16 copies
// made in d_ws; gates + h-recurrence accumulate in fp32.
//   1. cvt: fp32 -> bf16 copies of x, W_ih, W_hh in ws.
//   2. Gx[b][15+l][g] = x[b][l]*W_ih^T + b_ih (bf16, token-indexed, pad rows
//      0..14 hold b_ih). 25.5 MB in ws.
//   3. rnn_main: 256 blocks x 1024 thr; block owns 64 positions, h-prev in
//      LDS (bf16, MFMA A operand) + fp32 register copy for the z*h term.

#define B_  16
#define L_  1024
#define D_  256
#define H_  256
#define K_  16
#define G3  768            // 3*H
#define LP  (L_ + K_ - 1)  // 1039 padded token rows per batch
#define MT  64             // positions per block (main kernel)
#define HS  264            // LDS row stride (bf16 units): 256+8 -> 2-way alias only

typedef __attribute__((ext_vector_type(8))) short  bf16x8;
typedef __attribute__((ext_vector_type(4))) float  floatx4;
typedef unsigned short ush;

__device__ __forceinline__ ush f2bf(float f) {
    union { float f; unsigned int i; } v; v.f = f;
    unsigned int x = v.i;
    return (ush)((x + 0x7FFFu + ((x >> 16) & 1u)) >> 16);  // RNE
}
__device__ __forceinline__ float fsig(float x) {
    return 1.f / (1.f + __expf(-x));
}
__device__ __forceinline__ float ftanh_(float x) {
    x = fminf(15.f, fmaxf(-15.f, x));
    float e = __expf(2.f * x);
    return (e - 1.f) / (e + 1.f);
}

// ---- fp32 -> bf16 copy (n divisible by 4) ---------------------------------
__global__ void cvt(const float* __restrict__ src, ush* __restrict__ dst, int n) {
    int i = (blockIdx.x * blockDim.x + threadIdx.x) * 4;
    if (i >= n) return;
    float4 v = *(const float4*)(src + i);
    dst[i]     = f2bf(v.x);
    dst[i + 1] = f2bf(v.y);
    dst[i + 2] = f2bf(v.z);
    dst[i + 3] = f2bf(v.w);
}

// ---- pad rows of Gx: gi for zero input = b_ih ------------------------------
__global__ void fill_pad(const float* __restrict__ b_ih, ush* __restrict__ Gx) {
    int idx = blockIdx.x * blockDim.x + threadIdx.x;
    if (idx >= B_ * (K_ - 1) * G3) return;
    int g  = idx % G3;
    int rb = idx / G3;
    int b  = rb / (K_ - 1);
    int r  = rb % (K_ - 1);
    Gx[((size_t)b * LP + r) * G3 + g] = f2bf(b_ih[g]);
}

// ---- Gx GEMM: [16384,256] x [256,768] (NT), bias folded --------------------
__global__ __launch_bounds__(256) void gx_gemm(const ush* __restrict__ xb,
                                               const ush* __restrict__ Wb,
                                               const float* __restrict__ b_ih,
                                               ush* __restrict__ Gx) {
    int m0   = blockIdx.x * 64;
    int n0   = blockIdx.y * 64;
    int wave = threadIdx.x >> 6;
    int lane = threadIdx.x & 63;
    int l16  = lane & 15, quad = lane >> 4;

    const ush* xa = xb + (size_t)(m0 + wave * 16 + l16) * D_ + quad * 8;

    floatx4 acc[4];
    for (int nt = 0; nt < 4; nt++) {
        float bias = b_ih[n0 + nt * 16 + l16];
        acc[nt] = (floatx4){bias, bias, bias, bias};
    }
    for (int ks = 0; ks < 8; ks++) {
        bf16x8 afrag = *(const bf16x8*)(xa + ks * 32);
        for (int nt = 0; nt < 4; nt++) {
            const ush* wp = Wb + (size_t)(n0 + nt * 16 + l16) * D_ + ks * 32 + quad * 8;
            bf16x8 bfrag = *(const bf16x8*)wp;
            acc[nt] = __builtin_amdgcn_mfma_f32_16x16x32_bf16(afrag, bfrag, acc[nt], 0, 0, 0);
        }
    }
    // C/D: col = lane&15 (n), row = quad*4 + reg (m)
    for (int nt = 0; nt < 4; nt++) {
        int n = n0 + nt * 16 + l16;
        for (int r = 0; r < 4; r++) {
            int m = m0 + wave * 16 + quad * 4 + r;
            int b = m >> 10, l = m & 1023;
            Gx[((size_t)b * LP + (K_ - 1) + l) * G3 + n] = f2bf(acc[nt][r]);
        }
    }
}

// ---- recurrent GRU kernel --------------------------------------------------
__global__ __launch_bounds__(1024) void rnn_main(const ush* __restrict__ Gx,
                                                 const ush* __restrict__ Wb,
                                                 const float* __restrict__ b_hh,
                                                 float* __restrict__ out) {
    __shared__ ush hl[MT * HS];  // 64 x 264 bf16 = 33 KB

    int tid  = threadIdx.x;
    int wave = tid >> 6, lane = tid & 63;
    int l16  = lane & 15, quad = lane >> 4;
    int i0   = wave * 16;           // this wave's hidden-column stripe
    int p0   = blockIdx.x * MT;     // first global position of the block
    int bb   = p0 >> 10;            // batch (MT divides L so tile is intra-batch)
    int l0   = p0 & 1023;

    // zero h in LDS
    for (int idx = tid; idx < MT * HS / 2; idx += 1024)
        ((unsigned int*)hl)[idx] = 0u;

    int   i      = i0 + l16;
    float bias_r = b_hh[i];
    float bias_z = b_hh[256 + i];
    float bias_n = b_hh[512 + i];

    float hreg[16];  // fp32 h for this thread's (mloc, i) cells
    for (int q = 0; q < 16; q++) hreg[q] = 0.f;

    for (int t = 0; t < K_; t++) {
        __syncthreads();  // h (t-1) LDS writes visible to all waves

        floatx4 acc[4][3];
        for (int mc = 0; mc < 4; mc++) {
            acc[mc][0] = (floatx4){bias_r, bias_r, bias_r, bias_r};
            acc[mc][1] = (floatx4){bias_z, bias_z, bias_z, bias_z};
            acc[mc][2] = (floatx4){bias_n, bias_n, bias_n, bias_n};
        }
        // gh = h * W_hh^T  (K = 256, 8 k-steps of 32)
        for (int ks = 0; ks < 8; ks++) {
            bf16x8 bfr[3];
            for (int gt = 0; gt < 3; gt++) {
                const ush* wp = Wb + (size_t)(gt * 256 + i) * H_ + ks * 32 + quad * 8;
                bfr[gt] = *(const bf16x8*)wp;
            }
            for (int mc = 0; mc < 4; mc++) {
                bf16x8 afr = *(const bf16x8*)(hl + (mc * 16 + l16) * HS + ks * 32 + quad * 8);
                acc[mc][0] = __builtin_amdgcn_mfma_f32_16x16x32_bf16(afr, bfr[0], acc[mc][0], 0, 0, 0);
                acc[mc][1] = __builtin_amdgcn_mfma_f32_16x16x32_bf16(afr, bfr[1], acc[mc][1], 0, 0, 0);
                acc[mc][2] = __builtin_amdgcn_mfma_f32_16x16x32_bf16(afr, bfr[2], acc[mc][2], 0, 0, 0);
            }
        }
        // gates (C/D: col = l16 -> hidden col i, row = quad*4+reg -> position)
        const ush* gxb = Gx + ((size_t)bb * LP + l0 + t) * G3;
        float hnew[16];
        for (int mc = 0; mc < 4; mc++) {
            for (int r = 0; r < 4; r++) {
                int mloc = mc * 16 + quad * 4 + r;
                const ush* gx = gxb + (size_t)mloc * G3;
                float ir  = __bfloat162float(*(const __hip_bfloat16*)(gx + i));
                float iz  = __bfloat162float(*(const __hip_bfloat16*)(gx + 256 + i));
                float inn = __bfloat162float(*(const __hip_bfloat16*)(gx + 512 + i));
                float rg = fsig(ir + acc[mc][0][r]);
                float zg = fsig(iz + acc[mc][1][r]);
                float ng = ftanh_(inn + rg * acc[mc][2][r]);
                float ho = hreg[mc * 4 + r];
                hnew[mc * 4 + r] = (1.f - zg) * ng + zg * ho;
            }
        }
        __syncthreads();  // all A-frag reads for step t complete
        for (int mc = 0; mc < 4; mc++)
            for (int r = 0; r < 4; r++) {
                int mloc = mc * 16 + quad * 4 + r;
                ush hb = f2bf(hnew[mc * 4 + r]);
                hl[mloc * HS + i] = hb;
                hreg[mc * 4 + r] = hnew[mc * 4 + r];
            }
    }
    // final h -> out[b][l][i]  (fp32)
    for (int mc = 0; mc < 4; mc++)
        for (int r = 0; r < 4; r++) {
            int mloc = mc * 16 + quad * 4 + r;
            out[(size_t)(p0 + mloc) * H_ + i] = hreg[mc * 4 + r];
        }
}

extern "C" void kernel_launch(void* const* d_in, const int* in_sizes, int n_in,
                              void* d_out, int out_size, void* d_ws, size_t ws_size,
                              hipStream_t stream) {
    const float* x    = (const float*)d_in[0];
    const float* W_ih = (const float*)d_in[1];
    const float* W_hh = (const float*)d_in[2];
    const float* b_ih = (const float*)d_in[3];
    const float* b_hh = (const float*)d_in[4];
    float* out = (float*)d_out;

    // ws layout (bytes):
    //   Gx    : B*LP*G3 bf16          = 25,534,464
    //   xb    : B*L*D bf16            =  8,388,608
    //   Wb_ih : G3*D bf16             =    393,216
    //   Wb_hh : G3*H bf16             =    393,216
    char* ws = (char*)d_ws;
    ush* Gx    = (ush*)ws;
    ush* xb    = (ush*)(ws + 25534464);
    ush* Wb_ih = (ush*)(ws + 25534464 + 8388608);
    ush* Wb_hh = (ush*)(ws + 25534464 + 8388608 + 393216);

    int nx = B_ * L_ * D_;       // 4,194,304
    int nw = G3 * D_;            // 196,608
    cvt<<<(nx / 4 + 255) / 256, 256, 0, stream>>>(x, xb, nx);
    cvt<<<(nw / 4 + 255) / 256, 256, 0, stream>>>(W_ih, Wb_ih, nw);
    cvt<<<(nw / 4 + 255) / 256, 256, 0, stream>>>(W_hh, Wb_hh, nw);

    fill_pad<<<(B_ * (K_ - 1) * G3 + 255) / 256, 256, 0, stream>>>(b_ih, Gx);
    dim3 g1(B_ * L_ / 64, G3 / 64);  // 256 x 12
    gx_gemm<<<g1, 256, 0, stream>>>(xb, Wb_ih, b_ih, Gx);
    rnn_main<<<B_ * L_ / MT, 1024, 0, stream>>>(Gx, Wb_hh, b_hh, out);
}

// Round 3
// 384.892 us; speedup vs baseline: 1.4262x; 1.4262x over previous
//
#include <hip/hip_runtime.h>
#include <hip/hip_bf16.h>
#include <cstdint>

// LocalRNN: B=16 L=1024 D=256 H=256 K=16, GRU over K-window per position.
// FP32 in/out. MFMA on bf16 copies; fp32 gates + recurrence.
//   1. cvt: fp32 -> bf16 copies of x, W_ih, W_hh in ws.
//   2. Gx[b][15+l][g] = x[b][l]*W_ih^T + b_ih (bf16, pad rows = b_ih). 25.5 MB ws.
//   3. rnn_main: 256 blocks (1/CU) x 1024 thr; block owns 64 positions.
//      Block's Gx slice (79 rows x 768) preloaded to LDS (kills the L2-thrashing
//      Gx stream so W_hh stays L2-resident); h in LDS bf16 + fp32 regs;
//      W_hh streamed from L2 per step.

#define B_  16
#define L_  1024
#define D_  256
#define H_  256
#define K_  16
#define G3  768            // 3*H
#define LP  (L_ + K_ - 1)  // 1039 padded token rows per batch
#define MT  64             // positions per block
#define HS  264            // h LDS row stride (bf16): 256+8 -> 2-way alias only
#define GROWS 79           // Gx rows per block = MT + K - 1
#define GSTR  776          // Gx LDS row stride (768+8): quad strides land 2-way

typedef __attribute__((ext_vector_type(8))) short  bf16x8;
typedef __attribute__((ext_vector_type(4))) float  floatx4;
typedef unsigned short ush;

__device__ __forceinline__ float bf2f(ush u) {
    union { unsigned int i; float f; } v; v.i = ((unsigned int)u) << 16; return v.f;
}
__device__ __forceinline__ ush f2bf(float f) {
    union { float f; unsigned int i; } v; v.f = f;
    unsigned int x = v.i;
    return (ush)((x + 0x7FFFu + ((x >> 16) & 1u)) >> 16);  // RNE
}
__device__ __forceinline__ float fsig(float x) {
    return 1.f / (1.f + __expf(-x));
}
__device__ __forceinline__ float ftanh_(float x) {
    x = fminf(15.f, fmaxf(-15.f, x));
    float e = __expf(2.f * x);
    return (e - 1.f) / (e + 1.f);
}

// ---- fp32 -> bf16 copy (n divisible by 4) ---------------------------------
__global__ void cvt(const float* __restrict__ src, ush* __restrict__ dst, int n) {
    int i = (blockIdx.x * blockDim.x + threadIdx.x) * 4;
    if (i >= n) return;
    float4 v = *(const float4*)(src + i);
    dst[i]     = f2bf(v.x);
    dst[i + 1] = f2bf(v.y);
    dst[i + 2] = f2bf(v.z);
    dst[i + 3] = f2bf(v.w);
}

// ---- pad rows of Gx: gi for zero input = b_ih ------------------------------
__global__ void fill_pad(const float* __restrict__ b_ih, ush* __restrict__ Gx) {
    int idx = blockIdx.x * blockDim.x + threadIdx.x;
    if (idx >= B_ * (K_ - 1) * G3) return;
    int g  = idx % G3;
    int rb = idx / G3;
    int b  = rb / (K_ - 1);
    int r  = rb % (K_ - 1);
    Gx[((size_t)b * LP + r) * G3 + g] = f2bf(b_ih[g]);
}

// ---- Gx GEMM: [16384,256] x [256,768] (NT), bias folded --------------------
__global__ __launch_bounds__(256) void gx_gemm(const ush* __restrict__ xb,
                                               const ush* __restrict__ Wb,
                                               const float* __restrict__ b_ih,
                                               ush* __restrict__ Gx) {
    int m0   = blockIdx.x * 64;
    int n0   = blockIdx.y * 64;
    int wave = threadIdx.x >> 6;
    int lane = threadIdx.x & 63;
    int l16  = lane & 15, quad = lane >> 4;

    const ush* xa = xb + (size_t)(m0 + wave * 16 + l16) * D_ + quad * 8;

    floatx4 acc[4];
    for (int nt = 0; nt < 4; nt++) {
        float bias = b_ih[n0 + nt * 16 + l16];
        acc[nt] = (floatx4){bias, bias, bias, bias};
    }
    for (int ks = 0; ks < 8; ks++) {
        bf16x8 afrag = *(const bf16x8*)(xa + ks * 32);
        for (int nt = 0; nt < 4; nt++) {
            const ush* wp = Wb + (size_t)(n0 + nt * 16 + l16) * D_ + ks * 32 + quad * 8;
            bf16x8 bfrag = *(const bf16x8*)wp;
            acc[nt] = __builtin_amdgcn_mfma_f32_16x16x32_bf16(afrag, bfrag, acc[nt], 0, 0, 0);
        }
    }
    // C/D: col = lane&15 (n), row = quad*4 + reg (m)
    for (int nt = 0; nt < 4; nt++) {
        int n = n0 + nt * 16 + l16;
        for (int r = 0; r < 4; r++) {
            int m = m0 + wave * 16 + quad * 4 + r;
            int b = m >> 10, l = m & 1023;
            Gx[((size_t)b * LP + (K_ - 1) + l) * G3 + n] = f2bf(acc[nt][r]);
        }
    }
}

// ---- recurrent GRU kernel --------------------------------------------------
__global__ __launch_bounds__(1024) void rnn_main(const ush* __restrict__ Gx,
                                                 const ush* __restrict__ Wb,
                                                 const float* __restrict__ b_hh,
                                                 float* __restrict__ out) {
    __shared__ __align__(16) ush gil[GROWS * GSTR];  // 122,608 B
    __shared__ __align__(16) ush hl[MT * HS];        //  33,792 B  (total 156.4 KB)

    int tid  = threadIdx.x;
    int wave = tid >> 6, lane = tid & 63;
    int l16  = lane & 15, quad = lane >> 4;
    int i0   = wave * 16;
    int p0   = blockIdx.x * MT;
    int bb   = p0 >> 10;
    int l0   = p0 & 1023;
    int i    = i0 + l16;

    // ---- preload this block's Gx slice (rows l0..l0+78) into LDS, coalesced
    const ush* gsrc = Gx + ((size_t)bb * LP + l0) * G3;  // 16B-aligned (768*2B rows)
    for (int idx = tid; idx < GROWS * 96; idx += 1024) {
        int row = idx / 96, c = idx % 96;  // 96 chunks of 8 ush per row
        *(float4*)(gil + row * GSTR + c * 8) =
            *(const float4*)(gsrc + (size_t)row * G3 + c * 8);
    }
    // ---- zero h
    for (int idx = tid; idx < MT * HS / 2; idx += 1024)
        ((unsigned int*)hl)[idx] = 0u;

    float bias_r = b_hh[i];
    float bias_z = b_hh[256 + i];
    float bias_n = b_hh[512 + i];

    float hreg[16];
    for (int q = 0; q < 16; q++) hreg[q] = 0.f;

    for (int t = 0; t < K_; t++) {
        __syncthreads();  // fill/h(t-1) visible to all waves

        // acc init: gi_r/gi_z folded in; n-gate starts at b_hh only
        // (torch GRU: n = tanh(i_n + r*(h.Whn + b_hn)) — i_n must stay outside r*)
        floatx4 acc[4][3];
        for (int mc = 0; mc < 4; mc++) {
            int rb = t + mc * 16 + quad * 4;
            for (int r = 0; r < 4; r++) {
                const ush* gp = gil + (rb + r) * GSTR;
                acc[mc][0][r] = bias_r + bf2f(gp[i]);
                acc[mc][1][r] = bias_z + bf2f(gp[256 + i]);
                acc[mc][2][r] = bias_n;
            }
        }
        // gh = h * W_hh^T  (K = 256, 8 k-steps of 32); W streamed from L2
#pragma unroll
        for (int ks = 0; ks < 8; ks++) {
            bf16x8 bfr[3];
            for (int gt = 0; gt < 3; gt++) {
                const ush* wp = Wb + (size_t)(gt * 256 + i) * H_ + ks * 32 + quad * 8;
                bfr[gt] = *(const bf16x8*)wp;
            }
            for (int mc = 0; mc < 4; mc++) {
                bf16x8 afr = *(const bf16x8*)(hl + (mc * 16 + l16) * HS + ks * 32 + quad * 8);
                acc[mc][0] = __builtin_amdgcn_mfma_f32_16x16x32_bf16(afr, bfr[0], acc[mc][0], 0, 0, 0);
                acc[mc][1] = __builtin_amdgcn_mfma_f32_16x16x32_bf16(afr, bfr[1], acc[mc][1], 0, 0, 0);
                acc[mc][2] = __builtin_amdgcn_mfma_f32_16x16x32_bf16(afr, bfr[2], acc[mc][2], 0, 0, 0);
            }
        }
        // gates (C/D: col = l16 -> hidden col i, row = quad*4+reg -> position)
        float hnew[16];
        for (int mc = 0; mc < 4; mc++) {
            for (int r = 0; r < 4; r++) {
                int mloc = mc * 16 + quad * 4 + r;
                float inn = bf2f(gil[(t + mloc) * GSTR + 512 + i]);
                float rg = fsig(acc[mc][0][r]);
                float zg = fsig(acc[mc][1][r]);
                float ng = ftanh_(inn + rg * acc[mc][2][r]);
                hnew[mc * 4 + r] = (1.f - zg) * ng + zg * hreg[mc * 4 + r];
            }
        }
        __syncthreads();  // all A-frag reads for step t complete
        for (int mc = 0; mc < 4; mc++)
            for (int r = 0; r < 4; r++) {
                int mloc = mc * 16 + quad * 4 + r;
                hl[mloc * HS + i] = f2bf(hnew[mc * 4 + r]);
                hreg[mc * 4 + r] = hnew[mc * 4 + r];
            }
    }
    // final h -> out[b][l][i]  (fp32)
    for (int mc = 0; mc < 4; mc++)
        for (int r = 0; r < 4; r++) {
            int mloc = mc * 16 + quad * 4 + r;
            out[(size_t)(p0 + mloc) * H_ + i] = hreg[mc * 4 + r];
        }
}

extern "C" void kernel_launch(void* const* d_in, const int* in_sizes, int n_in,
                              void* d_out, int out_size, void* d_ws, size_t ws_size,
                              hipStream_t stream) {
    const float* x    = (const float*)d_in[0];
    const float* W_ih = (const float*)d_in[1];
    const float* W_hh = (const float*)d_in[2];
    const float* b_ih = (const float*)d_in[3];
    const float* b_hh = (const float*)d_in[4];
    float* out = (float*)d_out;

    // ws layout (bytes): Gx 25,534,464 | xb 8,388,608 | Wb_ih 393,216 | Wb_hh 393,216
    char* ws = (char*)d_ws;
    ush* Gx    = (ush*)ws;
    ush* xb    = (ush*)(ws + 25534464);
    ush* Wb_ih = (ush*)(ws + 25534464 + 8388608);
    ush* Wb_hh = (ush*)(ws + 25534464 + 8388608 + 393216);

    int nx = B_ * L_ * D_;  // 4,194,304
    int nw = G3 * D_;       // 196,608
    cvt<<<(nx / 4 + 255) / 256, 256, 0, stream>>>(x, xb, nx);
    cvt<<<(nw / 4 + 255) / 256, 256, 0, stream>>>(W_ih, Wb_ih, nw);
    cvt<<<(nw / 4 + 255) / 256, 256, 0, stream>>>(W_hh, Wb_hh, nw);

    fill_pad<<<(B_ * (K_ - 1) * G3 + 255) / 256, 256, 0, stream>>>(b_ih, Gx);
    dim3 g1(B_ * L_ / 64, G3 / 64);  // 256 x 12
    gx_gemm<<<g1, 256, 0, stream>>>(xb, Wb_ih, b_ih, Gx);
    rnn_main<<<B_ * L_ / MT, 1024, 0, stream>>>(Gx, Wb_hh, b_hh, out);
}